// Round 3
// baseline (120854.358 us; speedup 1.0000x reference)
//
#include <hip/hip_runtime.h>
#include <math.h>

#define Tt 512
#define Dd 768
#define Hh 512
#define Bb 32
#define G3 1536
#define HB (Hh*Bb)
#define NBLK 128          // 128 row-blocks x 4 rows per gate-group (weight rows read ONCE, x32 batch reuse)
#define NTHR 512
#define NGRP 8            // 128 blocks = 8 groups x 16
#define NBAR (Tt*4)       // 4 grid barriers per step (proven structure)
#define PR 32             // state ring period (staleness window; L2 churn evicts 32-step-old lines)

__device__ __forceinline__ float sigf(float x) { return 1.f / (1.f + expf(-x)); }

// device-scope write-through store: lands at coherence point, no fence needed
__device__ __forceinline__ void dstore(float* p, float v) {
  __hip_atomic_store(p, v, __ATOMIC_RELAXED, __HIP_MEMORY_SCOPE_AGENT);
}

// ---------------- grid barrier: relaxed monotone atomics, two-level tree ----
__device__ __forceinline__ void grid_barrier(unsigned* bc1, unsigned* bc2, unsigned* gfl, int idx)
{
  __syncthreads();
  if (threadIdx.x == 0) {
    const unsigned grp = (unsigned)(blockIdx.x >> 4);     // 8 groups x 16 blocks
    unsigned old = __hip_atomic_fetch_add(&bc1[((unsigned)idx * NGRP + grp) * 16u], 1u,
                        __ATOMIC_RELAXED, __HIP_MEMORY_SCOPE_AGENT);
    if (old == 15u) {
      unsigned o2 = __hip_atomic_fetch_add(&bc2[(unsigned)idx * 16u], 1u,
                        __ATOMIC_RELAXED, __HIP_MEMORY_SCOPE_AGENT);
      if (o2 == (unsigned)(NGRP - 1)) {
#pragma unroll
        for (int g = 0; g < NGRP; ++g)
          __hip_atomic_store(&gfl[g * 16], (unsigned)(idx + 1),
                             __ATOMIC_RELAXED, __HIP_MEMORY_SCOPE_AGENT);
      }
    }
    while (__hip_atomic_load(&gfl[grp * 16], __ATOMIC_RELAXED, __HIP_MEMORY_SCOPE_AGENT)
           < (unsigned)(idx + 1))
      __builtin_amdgcn_s_sleep(4);
  }
  __syncthreads();
}

// ---------------- GI0 = x @ Wih0^T + bih0, layout [t][j][b] ----------------
__global__ __launch_bounds__(256) void gi0_gemm(const float* __restrict__ x,
                                                const float* __restrict__ Wih0,
                                                const float* __restrict__ bih0,
                                                float* __restrict__ GI0)
{
  const int t  = blockIdx.x;
  const int j0 = blockIdx.y * 128;
  const int tid = threadIdx.x;
  const int b = tid & 31, u = tid >> 5;

  __shared__ float xs[128][33];
  float acc[16];
#pragma unroll
  for (int jj = 0; jj < 16; jj++) acc[jj] = 0.f;

  for (int kbv = 0; kbv < Dd; kbv += 128) {
    __syncthreads();
    {
      int bb = tid >> 3, kg = (tid & 7) * 4;
      const float* xp = x + ((size_t)bb * Tt + t) * Dd + kbv;
#pragma unroll
      for (int q = 0; q < 4; q++) {
        float4 v = *(const float4*)(xp + kg + q * 32);
        int k = kg + q * 32;
        xs[k + 0][bb] = v.x; xs[k + 1][bb] = v.y;
        xs[k + 2][bb] = v.z; xs[k + 3][bb] = v.w;
      }
    }
    __syncthreads();
    for (int kk = 0; kk < 128; kk += 4) {
      float x0 = xs[kk][b], x1 = xs[kk + 1][b], x2 = xs[kk + 2][b], x3 = xs[kk + 3][b];
#pragma unroll
      for (int jj = 0; jj < 16; jj++) {
        const float* wp = Wih0 + (size_t)(j0 + u + 8 * jj) * Dd + kbv + kk;
        float4 w4 = *(const float4*)wp;
        acc[jj] += w4.x * x0 + w4.y * x1 + w4.z * x2 + w4.w * x3;
      }
    }
  }
#pragma unroll
  for (int jj = 0; jj < 16; jj++) {
    int j = j0 + u + 8 * jj;
    GI0[((size_t)t * G3 + j) * 32 + b] = acc[jj] + bih0[j];
  }
}

// ---------------- persistent HRNN kernel: 128 row-blocks, 4 barriers/step ----------------
__global__ __launch_bounds__(NTHR, 1) void hrnn_persist(
    const float* __restrict__ Whh0, const float* __restrict__ bhh0,
    const float* __restrict__ Wih,  const float* __restrict__ Whh,
    const float* __restrict__ bih,  const float* __restrict__ bhh,
    const float* __restrict__ mW1,  const float* __restrict__ mb1,
    const float* __restrict__ mW2,  const float* __restrict__ mb2,
    const float* __restrict__ mW3,  const float* __restrict__ mb3,
    const float* __restrict__ GI0,
    float* __restrict__ c0R, float* __restrict__ c1R, float* __restrict__ c2R,
    float* __restrict__ m0aR, float* __restrict__ m1aR,
    float* __restrict__ pacc,
    unsigned* __restrict__ bc1, unsigned* __restrict__ bc2, unsigned* __restrict__ gfl,
    float* __restrict__ out)
{
  __shared__ float red[16][640];
  __shared__ float s_pre[12][32];   // layer0 gate preacts (gh+bias+GI0 r/z)
  __shared__ float s_gh1[12][32];   // layer1 gh (+bhh)
  __shared__ float s_gh2[12][32];   // layer2 gh (+bhh)
  __shared__ float s_gi[12][32];    // gi of current phase
  __shared__ float s_ab[7][32];     // a0,a1,a2,w10,w11,p0,p1
  __shared__ float s_mb[4][32];     // m0b/m1b rows of this block

  const int tid = threadIdx.x;
  const int b = tid & 31;
  const int u = tid >> 5;          // 0..15
  const int kb = u * 32;
  const int i0 = blockIdx.x * 4;
  const int grp = blockIdx.x >> 4;
  int baridx = 0;

  // ---- hoisted per-thread constants (uniform across steps) ----
  float b_r1a, b_r1b = 0.f, b_r2a, b_r2b = 0.f, b_s2, b_s3a, b_s3b = 0.f, b_s4 = 0.f;
  float w3p[4] = {0,0,0,0}, w3q[4] = {0,0,0,0};
  float mb3v = 0.f;
  {
    int w = tid >> 5;
    // S1 round1 pass A (w 0..15)
    if (w < 12) b_r1a = bhh0[(w >> 2) * 512 + i0 + (w & 3)];
    else { int rem = w - 12; b_r1a = bhh[(rem >> 2) * 512 + i0 + (rem & 3)]; }
    // S1 round1 pass B (tid<64 -> w 16,17 -> l=1 rem 4,5)
    if (tid < 64) { int rem = 16 + (tid >> 5) - 12; b_r1b = bhh[(rem >> 2) * 512 + i0 + (rem & 3)]; }
    // S1 round2 pass A (w 18..33): l = w/12, rem = w%12
    { int w2 = w + 18, l = w2 / 12, rem = w2 % 12;
      int row = (rem >> 2) * 512 + i0 + (rem & 3);
      b_r2a = (l == 1) ? bhh[row] : bhh[G3 + row]; }
    // S1 round2 pass B (tid<64 -> w 34,35 -> l=2 rem 10,11)
    if (tid < 64) { int rem = 34 + (tid >> 5) - 24; b_r2b = bhh[G3 + (rem >> 2) * 512 + i0 + (rem & 3)]; }
    // S2 (w 0..15)
    if (w < 12) b_s2 = bih[(w >> 2) * 512 + i0 + (w & 3)];
    else b_s2 = mb1[i0 + (w - 12)];
    // S3 pass A (w 0..15)
    if (w < 12) b_s3a = bih[G3 + (w >> 2) * 512 + i0 + (w & 3)];
    else b_s3a = mb2[i0 + (w - 12)];
    // S3 pass B (tid<128 -> w 16..19 -> m1a cols)
    if (tid < 128) b_s3b = mb1[512 + i0 + (tid >> 5)];
    // S4 (tid<128 -> w 0..3)
    if (tid < 128) b_s4 = mb2[512 + i0 + (tid >> 5)];
    // p-partial weights (tid 128..159)
    if (tid >= 128 && tid < 160) {
#pragma unroll
      for (int r = 0; r < 4; r++) { w3p[r] = mW3[i0 + r]; w3q[r] = mW3[512 + i0 + r]; }
    }
    if (tid < 64) mb3v = mb3[tid >> 5];
  }

  for (int t = 0; t < Tt; t++) {
    const size_t wo = (size_t)(t & (PR - 1)) * HB;
    const size_t ro = (size_t)((t + PR - 1) & (PR - 1)) * HB;
    const float* c0o = c0R + ro;
    const float* c1o = c1R + ro;
    const float* c2o = c2R + ro;

    // ---- p-phase: reduce p-partials of step t-1 (8 buckets), softmax weights ----
    {
      const int pslot = (t + Tt - 1) & (Tt - 1);   // t=0 -> slot 511 (zeros)
      if (tid < 64) {
        int which = tid >> 5, b2 = tid & 31;
        const float* pp = pacc + ((size_t)pslot * 2 + which) * 512;
        float s = mb3v;
#pragma unroll
        for (int g = 0; g < NGRP; g++) s += pp[g * 32 + b2];
        s_ab[5 + which][b2] = sigf(s);
      }
      __syncthreads();
      if (tid < 32) {
        float p0 = s_ab[5][tid], p1 = s_ab[6][tid];
        float e0 = expf(1.f - p0), e1 = expf(p0 * (1.f - p1)), e2 = expf(p0 * p1);
        float inv = 1.f / (e0 + e1 + e2);
        s_ab[0][tid] = e0 * inv; s_ab[1][tid] = e1 * inv; s_ab[2][tid] = e2 * inv;
        float q0 = expf(1.f - p1), q1 = expf(p1);
        float qi = 1.f / (q0 + q1);
        s_ab[3][tid] = q0 * qi; s_ab[4][tid] = q1 * qi;
        if (t > 0 && blockIdx.x == 0) {
          out[((size_t)tid * Tt + (t - 1)) * 2 + 0] = p0;
          out[((size_t)tid * Tt + (t - 1)) * 2 + 1] = p1;
        }
      }
      __syncthreads();
    }

    const float a0 = s_ab[0][b], a1 = s_ab[1][b], a2 = s_ab[2][b];
    const float w10 = s_ab[3][b], w11 = s_ab[4][b];

    // ---- S1: gh0/gh1/gh2 with inline h-mixing; cell0 ----
    {
      // prefetch tail operands first (small, oldest in queue)
      float pf0 = 0.f, pf1 = 0.f, pf2 = 0.f, gi_n = 0.f;
      if (tid < 128) {
        int ii = tid >> 5, bb = tid & 31, idx = (i0 + ii) * 32 + bb;
        pf0 = c0o[idx]; pf1 = c1o[idx]; pf2 = c2o[idx];
        gi_n = GI0[((size_t)t * G3 + 1024 + i0 + ii) * 32 + bb];
      }
      float gi_rz = 0.f;
      if (tid < 256) {
        int w = tid >> 5, b2 = tid & 31;
        int row = (w >> 2) * 512 + i0 + (w & 3);
        gi_rz = GI0[((size_t)t * G3 + row) * 32 + b2];
      }

      float acc[36];
#pragma unroll
      for (int w = 0; w < 36; w++) acc[w] = 0.f;
      for (int h = 0; h < 2; ++h) {
        const int kh = kb + h * 16;
        float m0[16], m1[16], m2[16];
#pragma unroll
        for (int k = 0; k < 16; k++) {
          float v0 = c0o[(kh + k) * 32 + b];
          float v1 = c1o[(kh + k) * 32 + b];
          float v2 = c2o[(kh + k) * 32 + b];
          m0[k] = a0 * v0 + a1 * v1 + a2 * v2;
          m1[k] = w10 * v1 + w11 * v2;
          m2[k] = v2;
        }
#pragma unroll
        for (int kk = 0; kk < 16; kk += 4) {
#pragma unroll
          for (int w = 0; w < 36; w++) {
            const int l = w / 12, rem = w % 12;
            const int row = (rem >> 2) * 512 + i0 + (rem & 3);
            const float* wp = (l == 0) ? (Whh0 + (size_t)row * 512)
                            : (l == 1) ? (Whh  + (size_t)row * 512)
                                       : (Whh  + (size_t)(G3 + row) * 512);
            float4 w4 = *(const float4*)(wp + kh + kk);
            const float* mv = (l == 0) ? (m0 + kk) : (l == 1) ? (m1 + kk) : (m2 + kk);
            acc[w] += w4.x * mv[0] + w4.y * mv[1] + w4.z * mv[2] + w4.w * mv[3];
          }
        }
      }
      // reduce round 1 (w 0..17)
#pragma unroll
      for (int w = 0; w < 18; w++) red[u][w * 32 + b] = acc[w];
      __syncthreads();
      {
        float s = 0.f;
#pragma unroll
        for (int uu = 0; uu < 16; uu++) s += red[uu][tid];
        int w = tid >> 5, b2 = tid & 31;
        if (w < 12) {
          s += b_r1a;
          if (w < 8) s += gi_rz;
          s_pre[w][b2] = s;
        } else {
          s_gh1[w - 12][b2] = s + b_r1a;
        }
        if (tid < 64) {
          float s2 = 0.f;
#pragma unroll
          for (int uu = 0; uu < 16; uu++) s2 += red[uu][tid + 512];
          s_gh1[4 + (tid >> 5)][b2] = s2 + b_r1b;   // w 16,17 -> rem 4,5
        }
      }
      __syncthreads();
      // reduce round 2 (w 18..35)
#pragma unroll
      for (int w = 18; w < 36; w++) red[u][(w - 18) * 32 + b] = acc[w];
      __syncthreads();
      {
        float s = 0.f;
#pragma unroll
        for (int uu = 0; uu < 16; uu++) s += red[uu][tid];
        int w = (tid >> 5) + 18, b2 = tid & 31;
        int l = w / 12, rem = w % 12;
        if (l == 1) s_gh1[rem][b2] = s + b_r2a;
        else        s_gh2[rem][b2] = s + b_r2a;
        if (tid < 64) {
          float s2 = 0.f;
#pragma unroll
          for (int uu = 0; uu < 16; uu++) s2 += red[uu][tid + 512];
          s_gh2[10 + (tid >> 5)][b2] = s2 + b_r2b;  // w 34,35 -> l=2 rem 10,11
        }
      }
      __syncthreads();
      if (tid < 128) {
        int ii = tid >> 5, bb = tid & 31;
        float r = sigf(s_pre[ii][bb]);
        float z = sigf(s_pre[4 + ii][bb]);
        float n = tanhf(gi_n + r * s_pre[8 + ii][bb]);
        int idx = (i0 + ii) * 32 + bb;
        float h0old = a0 * pf0 + a1 * pf1 + a2 * pf2;
        dstore(&c0R[wo + idx], (1.f - z) * n + z * h0old);
      }
    }
    grid_barrier(bc1, bc2, gfl, baridx++);

    // ---- S2: gi1 (over cell0) + m0a; cell1 ----
    {
      float pf1 = 0.f, pf2 = 0.f;
      if (tid < 128) {
        int ii = tid >> 5, bb = tid & 31, idx = (i0 + ii) * 32 + bb;
        pf1 = c1o[idx]; pf2 = c2o[idx];
      }
      const float* c0n = c0R + wo;
      float v[32];
#pragma unroll
      for (int k = 0; k < 32; k++) v[k] = c0n[(kb + k) * 32 + b];
      float acc[16];
#pragma unroll
      for (int w = 0; w < 16; w++) acc[w] = 0.f;
#pragma unroll
      for (int kk = 0; kk < 32; kk += 4) {
#pragma unroll
        for (int w = 0; w < 16; w++) {
          const float* wp = (w < 12) ? (Wih + (size_t)((w >> 2) * 512 + i0 + (w & 3)) * 512)
                                     : (mW1 + (size_t)(i0 + (w - 12)) * 512);
          float4 w4 = *(const float4*)(wp + kb + kk);
          acc[w] += w4.x * v[kk] + w4.y * v[kk + 1] + w4.z * v[kk + 2] + w4.w * v[kk + 3];
        }
      }
#pragma unroll
      for (int w = 0; w < 16; w++) red[u][w * 32 + b] = acc[w];
      __syncthreads();
      {
        float s = 0.f;
#pragma unroll
        for (int uu = 0; uu < 16; uu++) s += red[uu][tid];
        int w = tid >> 5, b2 = tid & 31;
        if (w < 12) {
          s_gi[w][b2] = s + b_s2;
        } else {
          int col = i0 + (w - 12);
          dstore(&m0aR[wo + (size_t)col * 32 + b2], fmaxf(s + b_s2, 0.f));
        }
      }
      __syncthreads();
      if (tid < 128) {
        int ii = tid >> 5, bb = tid & 31;
        float r = sigf(s_gi[ii][bb] + s_gh1[ii][bb]);
        float z = sigf(s_gi[4 + ii][bb] + s_gh1[4 + ii][bb]);
        float n = tanhf(s_gi[8 + ii][bb] + r * s_gh1[8 + ii][bb]);
        int idx = (i0 + ii) * 32 + bb;
        float h1old = w10 * pf1 + w11 * pf2;
        dstore(&c1R[wo + idx], (1.f - z) * n + z * h1old);
      }
    }
    grid_barrier(bc1, bc2, gfl, baridx++);

    // ---- S3: gi2 (over cell1) + m0b (over m0a) + m1a (over cell1); cell2; p0 partials ----
    {
      float pf2 = 0.f;
      if (tid < 128) {
        int ii = tid >> 5, bb = tid & 31;
        pf2 = c2o[(i0 + ii) * 32 + bb];
      }
      const float* c1n = c1R + wo;
      const float* m0a = m0aR + wo;
      float v[32], vm[32];
#pragma unroll
      for (int k = 0; k < 32; k++) {
        v[k]  = c1n[(kb + k) * 32 + b];
        vm[k] = m0a[(kb + k) * 32 + b];
      }
      float acc[20];
#pragma unroll
      for (int w = 0; w < 20; w++) acc[w] = 0.f;
#pragma unroll
      for (int kk = 0; kk < 32; kk += 4) {
#pragma unroll
        for (int w = 0; w < 20; w++) {
          const float* wp = (w < 12) ? (Wih + (size_t)(G3 + (w >> 2) * 512 + i0 + (w & 3)) * 512)
                          : (w < 16) ? (mW2 + (size_t)(i0 + (w - 12)) * 512)
                                     : (mW1 + (size_t)(512 + i0 + (w - 16)) * 512);
          float4 w4 = *(const float4*)(wp + kb + kk);
          const float* src = (w >= 12 && w < 16) ? (vm + kk) : (v + kk);
          acc[w] += w4.x * src[0] + w4.y * src[1] + w4.z * src[2] + w4.w * src[3];
        }
      }
#pragma unroll
      for (int w = 0; w < 20; w++) red[u][w * 32 + b] = acc[w];
      __syncthreads();
      {
        float s = 0.f;
#pragma unroll
        for (int uu = 0; uu < 16; uu++) s += red[uu][tid];
        int w = tid >> 5, b2 = tid & 31;
        if (w < 12) {
          s_gi[w][b2] = s + b_s3a;
        } else {
          s_mb[w - 12][b2] = fmaxf(s + b_s3a, 0.f);   // m0b rows
        }
        if (tid < 128) {
          float s2 = 0.f;
#pragma unroll
          for (int uu = 0; uu < 16; uu++) s2 += red[uu][tid + 512];
          int col = i0 + (tid >> 5);                   // w 16..19 -> m1a cols
          dstore(&m1aR[wo + (size_t)col * 32 + b2], fmaxf(s2 + b_s3b, 0.f));
        }
      }
      __syncthreads();
      if (tid < 128) {
        int ii = tid >> 5, bb = tid & 31;
        float r = sigf(s_gi[ii][bb] + s_gh2[ii][bb]);
        float z = sigf(s_gi[4 + ii][bb] + s_gh2[4 + ii][bb]);
        float n = tanhf(s_gi[8 + ii][bb] + r * s_gh2[8 + ii][bb]);
        int idx = (i0 + ii) * 32 + bb;
        dstore(&c2R[wo + idx], (1.f - z) * n + z * pf2);
      } else if (tid < 160) {
        int b2 = tid - 128;
        float part = w3p[0] * s_mb[0][b2] + w3p[1] * s_mb[1][b2]
                   + w3p[2] * s_mb[2][b2] + w3p[3] * s_mb[3][b2];
        __hip_atomic_fetch_add(&pacc[((size_t)t * 2 + 0) * 512 + grp * 32 + b2], part,
                               __ATOMIC_RELAXED, __HIP_MEMORY_SCOPE_AGENT);
      }
    }
    grid_barrier(bc1, bc2, gfl, baridx++);

    // ---- S4: m1b (over m1a) + p1 partials ----
    {
      const float* m1a = m1aR + wo;
      float vm[32];
#pragma unroll
      for (int k = 0; k < 32; k++) vm[k] = m1a[(kb + k) * 32 + b];
      float acc[4];
#pragma unroll
      for (int w = 0; w < 4; w++) acc[w] = 0.f;
#pragma unroll
      for (int kk = 0; kk < 32; kk += 4) {
#pragma unroll
        for (int w = 0; w < 4; w++) {
          const float* wp = mW2 + (size_t)(512 + i0 + w) * 512;
          float4 w4 = *(const float4*)(wp + kb + kk);
          acc[w] += w4.x * vm[kk] + w4.y * vm[kk + 1] + w4.z * vm[kk + 2] + w4.w * vm[kk + 3];
        }
      }
#pragma unroll
      for (int w = 0; w < 4; w++) red[u][w * 32 + b] = acc[w];
      __syncthreads();
      if (tid < 128) {
        float s = 0.f;
#pragma unroll
        for (int uu = 0; uu < 16; uu++) s += red[uu][tid];
        int w = tid >> 5, b2 = tid & 31;
        s_mb[w][b2] = fmaxf(s + b_s4, 0.f);           // m1b rows
      }
      __syncthreads();
      if (tid >= 128 && tid < 160) {
        int b2 = tid - 128;
        float part = w3q[0] * s_mb[0][b2] + w3q[1] * s_mb[1][b2]
                   + w3q[2] * s_mb[2][b2] + w3q[3] * s_mb[3][b2];
        __hip_atomic_fetch_add(&pacc[((size_t)t * 2 + 1) * 512 + grp * 32 + b2], part,
                               __ATOMIC_RELAXED, __HIP_MEMORY_SCOPE_AGENT);
      }
    }
    grid_barrier(bc1, bc2, gfl, baridx++);
  }

  // ---- final output column t = T-1 ----
  if (blockIdx.x == 0 && tid < 64) {
    int which = tid >> 5, b2 = tid & 31;
    const float* pp = pacc + ((size_t)(Tt - 1) * 2 + which) * 512;
    float s = mb3v;
#pragma unroll
    for (int g = 0; g < NGRP; g++) s += pp[g * 32 + b2];
    out[((size_t)b2 * Tt + (Tt - 1)) * 2 + which] = sigf(s);
  }
}

extern "C" void kernel_launch(void* const* d_in, const int* in_sizes, int n_in,
                              void* d_out, int out_size, void* d_ws, size_t ws_size,
                              hipStream_t stream)
{
  (void)in_sizes; (void)n_in; (void)out_size;
  const float* x    = (const float*)d_in[0];
  const float* Wih0 = (const float*)d_in[1];
  const float* Whh0 = (const float*)d_in[2];
  const float* bih0 = (const float*)d_in[3];
  const float* bhh0 = (const float*)d_in[4];
  const float* Wih  = (const float*)d_in[5];
  const float* Whh  = (const float*)d_in[6];
  const float* bih  = (const float*)d_in[7];
  const float* bhh  = (const float*)d_in[8];
  const float* mW1  = (const float*)d_in[9];
  const float* mb1  = (const float*)d_in[10];
  const float* mW2  = (const float*)d_in[11];
  const float* mb2  = (const float*)d_in[12];
  const float* mW3  = (const float*)d_in[13];
  const float* mb3  = (const float*)d_in[14];
  float* out = (float*)d_out;

  char* ws = (char*)d_ws;
  size_t off = 0;
  auto take = [&](size_t bytes) { size_t o = off; off = (off + bytes + 255) & ~(size_t)255; return o; };
  unsigned* bc1 = (unsigned*)(ws + take((size_t)NBAR * NGRP * 16 * 4));
  unsigned* bc2 = (unsigned*)(ws + take((size_t)NBAR * 16 * 4));
  unsigned* gfl = (unsigned*)(ws + take((size_t)16 * 16 * 4));
  float* c0R  = (float*)(ws + take((size_t)PR * HB * 4));
  float* c1R  = (float*)(ws + take((size_t)PR * HB * 4));
  float* c2R  = (float*)(ws + take((size_t)PR * HB * 4));
  float* m0aR = (float*)(ws + take((size_t)PR * HB * 4));
  float* m1aR = (float*)(ws + take((size_t)PR * HB * 4));
  float* pacc = (float*)(ws + take((size_t)Tt * 2 * 512 * 4));
  size_t zero_bytes = off;
  float* GI0 = (float*)(ws + take((size_t)Tt * G3 * Bb * 4));
  if (ws_size < off) return;  // fail visibly rather than corrupt

  hipMemsetAsync(d_ws, 0, zero_bytes, stream);
  gi0_gemm<<<dim3(Tt, G3 / 128), 256, 0, stream>>>(x, Wih0, bih0, GI0);
  hrnn_persist<<<NBLK, NTHR, 0, stream>>>(Whh0, bhh0, Wih, Whh, bih, bhh,
      mW1, mb1, mW2, mb2, mW3, mb3, GI0,
      c0R, c1R, c2R, m0aR, m1aR, pacc, bc1, bc2, gfl, out);
}

// Round 4
// 24211.938 us; speedup vs baseline: 4.9915x; 4.9915x over previous
//
#include <hip/hip_runtime.h>
#include <math.h>

#define Tt 512
#define Dd 768
#define Hh 512
#define Bb 32
#define G3 1536
#define HB (Hh*Bb)
#define NBLK 256
#define NTHR 512
#define NBAR (Tt*4)
#define PR 32   // state ring period (staleness window; 32 steps ~ 330MB through 4MB L2)

__device__ __forceinline__ float sigf(float x) { return 1.f / (1.f + expf(-x)); }

__device__ __forceinline__ float dot4f(const float4 w4, const float* v) {
  return w4.x*v[0] + w4.y*v[1] + w4.z*v[2] + w4.w*v[3];
}

// device-scope write-through store: lands at coherence point, no fence needed
__device__ __forceinline__ void dstore(float* p, float v) {
  __hip_atomic_store(p, v, __ATOMIC_RELAXED, __HIP_MEMORY_SCOPE_AGENT);
}

// ---------------- grid barrier: relaxed monotone atomics, two-level tree ----
__device__ __forceinline__ void grid_barrier(unsigned* bc1, unsigned* bc2, unsigned* gfl, int idx)
{
  __syncthreads();
  if (threadIdx.x == 0) {
    const unsigned grp = (unsigned)(blockIdx.x >> 4);     // 16 groups x 16 blocks
    unsigned old = __hip_atomic_fetch_add(&bc1[((unsigned)idx * 16u + grp) * 16u], 1u,
                        __ATOMIC_RELAXED, __HIP_MEMORY_SCOPE_AGENT);
    if (old == 15u) {
      unsigned o2 = __hip_atomic_fetch_add(&bc2[(unsigned)idx * 16u], 1u,
                        __ATOMIC_RELAXED, __HIP_MEMORY_SCOPE_AGENT);
      if (o2 == 15u) {
#pragma unroll
        for (int g = 0; g < 16; ++g)
          __hip_atomic_store(&gfl[g * 16], (unsigned)(idx + 1),
                             __ATOMIC_RELAXED, __HIP_MEMORY_SCOPE_AGENT);
      }
    }
    while (__hip_atomic_load(&gfl[grp * 16], __ATOMIC_RELAXED, __HIP_MEMORY_SCOPE_AGENT)
           < (unsigned)(idx + 1))
      __builtin_amdgcn_s_sleep(4);
  }
  __syncthreads();
}

// ---------------- GI0 = x @ Wih0^T + bih0, layout [t][j][b] ----------------
__global__ __launch_bounds__(256) void gi0_gemm(const float* __restrict__ x,
                                                const float* __restrict__ Wih0,
                                                const float* __restrict__ bih0,
                                                float* __restrict__ GI0)
{
  const int t  = blockIdx.x;
  const int j0 = blockIdx.y * 128;
  const int tid = threadIdx.x;
  const int b = tid & 31, u = tid >> 5;

  __shared__ float xs[128][33];
  float acc[16];
#pragma unroll
  for (int jj = 0; jj < 16; jj++) acc[jj] = 0.f;

  for (int kbv = 0; kbv < Dd; kbv += 128) {
    __syncthreads();
    {
      int bb = tid >> 3, kg = (tid & 7) * 4;
      const float* xp = x + ((size_t)bb * Tt + t) * Dd + kbv;
#pragma unroll
      for (int q = 0; q < 4; q++) {
        float4 v = *(const float4*)(xp + kg + q * 32);
        int k = kg + q * 32;
        xs[k + 0][bb] = v.x; xs[k + 1][bb] = v.y;
        xs[k + 2][bb] = v.z; xs[k + 3][bb] = v.w;
      }
    }
    __syncthreads();
    for (int kk = 0; kk < 128; kk += 4) {
      float x0 = xs[kk][b], x1 = xs[kk + 1][b], x2 = xs[kk + 2][b], x3 = xs[kk + 3][b];
#pragma unroll
      for (int jj = 0; jj < 16; jj++) {
        const float* wp = Wih0 + (size_t)(j0 + u + 8 * jj) * Dd + kbv + kk;
        float4 w4 = *(const float4*)wp;
        acc[jj] += w4.x * x0 + w4.y * x1 + w4.z * x2 + w4.w * x3;
      }
    }
  }
#pragma unroll
  for (int jj = 0; jj < 16; jj++) {
    int j = j0 + u + 8 * jj;
    GI0[((size_t)t * G3 + j) * 32 + b] = acc[jj] + bih0[j];
  }
}

// ---------------- persistent HRNN kernel ----------------
__global__ __launch_bounds__(NTHR, 1) void hrnn_persist(
    const float* __restrict__ Whh0, const float* __restrict__ bhh0,
    const float* __restrict__ Wih,  const float* __restrict__ Whh,
    const float* __restrict__ bih,  const float* __restrict__ bhh,
    const float* __restrict__ mW1,  const float* __restrict__ mb1,
    const float* __restrict__ mW2,  const float* __restrict__ mb2,
    const float* __restrict__ mW3,  const float* __restrict__ mb3,
    const float* __restrict__ GI0,
    float* __restrict__ c0R, float* __restrict__ c1R, float* __restrict__ c2R,
    float* __restrict__ m0aR, float* __restrict__ m1aR,
    float* __restrict__ pacc,
    unsigned* __restrict__ bc1, unsigned* __restrict__ bc2, unsigned* __restrict__ gfl,
    float* __restrict__ out)
{
  __shared__ float red[16][576];
  __shared__ float s_gh[12][32];
  __shared__ float s_pre[6][32];
  __shared__ float s_gi[6][32];
  __shared__ float s_ab[7][32];    // a0,a1,a2,w10,w11,p0,p1
  __shared__ float s_mb[2][32];    // m0b or m1b columns of this block

  const int tid = threadIdx.x;
  const int b = tid & 31;
  const int u = tid >> 5;          // 0..15
  const int i0 = blockIdx.x * 2;
  const int kb = u * 32;
  const int grp = blockIdx.x >> 4;
  int baridx = 0;

  // hoisted scalars (uniform across steps)
  float mb3v = 0.f, w3p0 = 0.f, w3p1 = 0.f, w3q0 = 0.f, w3q1 = 0.f;
  if (tid < 64) mb3v = mb3[tid >> 5];
  if (tid >= 64 && tid < 96) {
    w3p0 = mW3[i0]; w3p1 = mW3[i0 + 1];
    w3q0 = mW3[512 + i0]; w3q1 = mW3[512 + i0 + 1];
  }

  for (int t = 0; t < Tt; t++) {
    const size_t wo = (size_t)(t & (PR - 1)) * HB;
    const size_t ro = (size_t)((t + PR - 1) & (PR - 1)) * HB;
    const float* c0o = c0R + ro;
    const float* c1o = c1R + ro;
    const float* c2o = c2R + ro;

    // ---- p-phase: read p-partial accumulators of step t-1 (4KB), softmax weights ----
    {
      const int pslot = (t + Tt - 1) & (Tt - 1);   // t=0 -> slot 511 (zeros)
      if (tid < 64) {
        int which = tid >> 5, b2 = tid & 31;
        const float* pp = pacc + ((size_t)pslot * 2 + which) * 512;
        float s = mb3v;
#pragma unroll
        for (int g = 0; g < 16; g++) s += pp[g * 32 + b2];
        s_ab[5 + which][b2] = sigf(s);
      }
      __syncthreads();
      if (tid < 32) {
        float p0 = s_ab[5][tid], p1 = s_ab[6][tid];
        float e0 = expf(1.f - p0), e1 = expf(p0 * (1.f - p1)), e2 = expf(p0 * p1);
        float inv = 1.f / (e0 + e1 + e2);
        s_ab[0][tid] = e0 * inv; s_ab[1][tid] = e1 * inv; s_ab[2][tid] = e2 * inv;
        float q0 = expf(1.f - p1), q1 = expf(p1);
        float qi = 1.f / (q0 + q1);
        s_ab[3][tid] = q0 * qi; s_ab[4][tid] = q1 * qi;
        if (t > 0 && blockIdx.x == 0) {
          out[((size_t)tid * Tt + (t - 1)) * 2 + 0] = p0;
          out[((size_t)tid * Tt + (t - 1)) * 2 + 1] = p1;
        }
      }
      __syncthreads();
    }

    const float a0 = s_ab[0][b], a1 = s_ab[1][b], a2 = s_ab[2][b];
    const float w10 = s_ab[3][b], w11 = s_ab[4][b];

    // ---- S1: gh0/gh1/gh2 with inline h-mixing; cell0 ----
    {
      // tail prefetch: issue early so MALL latency overlaps the matmul
      float pf0 = 0.f, pf1 = 0.f, pf2 = 0.f, gi_n = 0.f, gi_rz = 0.f;
      if (tid < 64) {
        int ii = tid >> 5, bb = tid & 31, idx = (i0 + ii) * 32 + bb;
        pf0 = c0o[idx]; pf1 = c1o[idx]; pf2 = c2o[idx];
        gi_n = GI0[((size_t)t * G3 + 1024 + i0 + ii) * 32 + bb];
      }
      if (tid < 128) {
        // w = tid>>5 in 0..3 -> g = w>>1, ii = w&1; row = g*512 + i0 + ii
        gi_rz = GI0[((size_t)t * G3 + (tid >> 6) * 512 + i0 + ((tid >> 5) & 1)) * 32 + (tid & 31)];
      }

      float acc[18];
#pragma unroll
      for (int w = 0; w < 18; w++) acc[w] = 0.f;

      // 2-deep pipelined k-loop: load next batch of 12 state floats before the 18 dots
      float v0[4], v1[4], v2[4];
#pragma unroll
      for (int q = 0; q < 4; q++) {
        int k = kb + q;
        v0[q] = c0o[k * 32 + b]; v1[q] = c1o[k * 32 + b]; v2[q] = c2o[k * 32 + b];
      }
      for (int kk = 0; kk < 32; kk += 4) {
        float n0[4], n1[4], n2[4];
        {
          int kn = kb + (kk < 28 ? kk + 4 : 4);   // last iter: dummy cached re-read
#pragma unroll
          for (int q = 0; q < 4; q++) {
            n0[q] = c0o[(kn + q) * 32 + b];
            n1[q] = c1o[(kn + q) * 32 + b];
            n2[q] = c2o[(kn + q) * 32 + b];
          }
        }
        float mh0[4], mh1[4];
#pragma unroll
        for (int q = 0; q < 4; q++) {
          mh0[q] = a0 * v0[q] + a1 * v1[q] + a2 * v2[q];
          mh1[q] = w10 * v1[q] + w11 * v2[q];
        }
#pragma unroll
        for (int w = 0; w < 18; w++) {
          const int l = w / 6, rem = w % 6, g = rem >> 1, ii = rem & 1;
          const int row = g * 512 + i0 + ii;
          const float* wp = (l == 0) ? (Whh0 + (size_t)row * 512)
                                     : (Whh + ((size_t)(l - 1) * G3 + row) * 512);
          float4 w4 = *(const float4*)(wp + kb + kk);
          acc[w] += (l == 0) ? dot4f(w4, mh0) : (l == 1) ? dot4f(w4, mh1) : dot4f(w4, v2);
        }
#pragma unroll
        for (int q = 0; q < 4; q++) { v0[q] = n0[q]; v1[q] = n1[q]; v2[q] = n2[q]; }
      }
#pragma unroll
      for (int w = 0; w < 18; w++) red[u][w * 32 + b] = acc[w];
      __syncthreads();
      for (int o = tid; o < 18 * 32; o += NTHR) {
        float s = 0.f;
#pragma unroll
        for (int uu = 0; uu < 16; uu++) s += red[uu][o];
        int w = o >> 5, b2 = o & 31;
        int l = w / 6, rem = w % 6, g = rem >> 1, ii = rem & 1;
        int row = g * 512 + i0 + ii;
        if (l == 0) {
          s += bhh0[row];
          if (g < 2) s += gi_rz;          // prefetched GI0 r/z (o==tid path only)
          s_pre[rem][b2] = s;
        } else if (l == 1) {
          s_gh[rem][b2] = s + bhh[row];
        } else {
          s_gh[6 + rem][b2] = s + bhh[G3 + row];
        }
      }
      __syncthreads();
      if (tid < 64) {
        int ii = tid >> 5, bb = tid & 31;
        float r = sigf(s_pre[ii][bb]);
        float z = sigf(s_pre[2 + ii][bb]);
        float n = tanhf(gi_n + r * s_pre[4 + ii][bb]);
        int idx = (i0 + ii) * 32 + bb;
        float h0old = a0 * pf0 + a1 * pf1 + a2 * pf2;
        dstore(&c0R[wo + idx], (1.f - z) * n + z * h0old);
      }
    }
    grid_barrier(bc1, bc2, gfl, baridx++);

    // ---- S2: gi1 (over cell0) + m0a; cell1 ----
    {
      float pf1 = 0.f, pf2 = 0.f;
      if (tid < 64) {
        int ii = tid >> 5, bb = tid & 31, idx = (i0 + ii) * 32 + bb;
        pf1 = c1o[idx]; pf2 = c2o[idx];
      }
      const float* c0n = c0R + wo;
      float acc[8];
#pragma unroll
      for (int w = 0; w < 8; w++) acc[w] = 0.f;
      float v[4];
#pragma unroll
      for (int q = 0; q < 4; q++) v[q] = c0n[(kb + q) * 32 + b];
      for (int kk = 0; kk < 32; kk += 4) {
        float nv[4];
        {
          int kn = kb + (kk < 28 ? kk + 4 : 4);
#pragma unroll
          for (int q = 0; q < 4; q++) nv[q] = c0n[(kn + q) * 32 + b];
        }
#pragma unroll
        for (int w = 0; w < 8; w++) {
          const float* wp = (w < 6) ? (Wih + (size_t)((w >> 1) * 512 + i0 + (w & 1)) * 512)
                                    : (mW1 + (size_t)(i0 + (w - 6)) * 512);
          float4 w4 = *(const float4*)(wp + kb + kk);
          acc[w] += dot4f(w4, v);
        }
#pragma unroll
        for (int q = 0; q < 4; q++) v[q] = nv[q];
      }
#pragma unroll
      for (int w = 0; w < 8; w++) red[u][w * 32 + b] = acc[w];
      __syncthreads();
      for (int o = tid; o < 8 * 32; o += NTHR) {
        float s = 0.f;
#pragma unroll
        for (int uu = 0; uu < 16; uu++) s += red[uu][o];
        int w = o >> 5, b2 = o & 31;
        if (w < 6) {
          int row = (w >> 1) * 512 + i0 + (w & 1);
          s_gi[w][b2] = s + bih[row];
        } else {
          int col = i0 + (w - 6);
          dstore(&m0aR[wo + col * 32 + b2], fmaxf(s + mb1[col], 0.f));
        }
      }
      __syncthreads();
      if (tid < 64) {
        int ii = tid >> 5, bb = tid & 31;
        float r = sigf(s_gi[ii][bb] + s_gh[ii][bb]);
        float z = sigf(s_gi[2 + ii][bb] + s_gh[2 + ii][bb]);
        float n = tanhf(s_gi[4 + ii][bb] + r * s_gh[4 + ii][bb]);
        int idx = (i0 + ii) * 32 + bb;
        float h1old = w10 * pf1 + w11 * pf2;
        dstore(&c1R[wo + idx], (1.f - z) * n + z * h1old);
      }
    }
    grid_barrier(bc1, bc2, gfl, baridx++);

    // ---- S3: gi2 (over cell1) + m0b (over m0a) + m1a (over cell1); cell2; p0 partials ----
    {
      float pf2 = 0.f;
      if (tid < 64) {
        int ii = tid >> 5, bb = tid & 31;
        pf2 = c2o[(i0 + ii) * 32 + bb];
      }
      const float* c1n = c1R + wo;
      const float* m0a = m0aR + wo;
      float acc[10];
#pragma unroll
      for (int w = 0; w < 10; w++) acc[w] = 0.f;
      float v[4], vm[4];
#pragma unroll
      for (int q = 0; q < 4; q++) {
        v[q]  = c1n[(kb + q) * 32 + b];
        vm[q] = m0a[(kb + q) * 32 + b];
      }
      for (int kk = 0; kk < 32; kk += 4) {
        float nv[4], nm[4];
        {
          int kn = kb + (kk < 28 ? kk + 4 : 4);
#pragma unroll
          for (int q = 0; q < 4; q++) {
            nv[q] = c1n[(kn + q) * 32 + b];
            nm[q] = m0a[(kn + q) * 32 + b];
          }
        }
#pragma unroll
        for (int w = 0; w < 10; w++) {
          const float* wp = (w < 6) ? (Wih + (size_t)(G3 + (w >> 1) * 512 + i0 + (w & 1)) * 512)
                          : (w < 8) ? (mW2 + (size_t)(i0 + (w - 6)) * 512)
                                    : (mW1 + (size_t)(512 + i0 + (w - 8)) * 512);
          float4 w4 = *(const float4*)(wp + kb + kk);
          acc[w] += dot4f(w4, (w < 6 || w >= 8) ? v : vm);
        }
#pragma unroll
        for (int q = 0; q < 4; q++) { v[q] = nv[q]; vm[q] = nm[q]; }
      }
#pragma unroll
      for (int w = 0; w < 10; w++) red[u][w * 32 + b] = acc[w];
      __syncthreads();
      for (int o = tid; o < 10 * 32; o += NTHR) {
        float s = 0.f;
#pragma unroll
        for (int uu = 0; uu < 16; uu++) s += red[uu][o];
        int w = o >> 5, b2 = o & 31;
        if (w < 6) {
          int row = (w >> 1) * 512 + i0 + (w & 1);
          s_gi[w][b2] = s + bih[G3 + row];
        } else if (w < 8) {
          s_mb[w - 6][b2] = fmaxf(s + mb2[i0 + (w - 6)], 0.f);   // m0b cols
        } else {
          int col = i0 + (w - 8);
          dstore(&m1aR[wo + col * 32 + b2], fmaxf(s + mb1[512 + col], 0.f));
        }
      }
      __syncthreads();
      if (tid < 64) {
        int ii = tid >> 5, bb = tid & 31;
        float r = sigf(s_gi[ii][bb] + s_gh[6 + ii][bb]);
        float z = sigf(s_gi[2 + ii][bb] + s_gh[8 + ii][bb]);
        float n = tanhf(s_gi[4 + ii][bb] + r * s_gh[10 + ii][bb]);
        int idx = (i0 + ii) * 32 + bb;
        dstore(&c2R[wo + idx], (1.f - z) * n + z * pf2);
      } else if (tid < 96) {
        int b2 = tid - 64;
        float part = w3p0 * s_mb[0][b2] + w3p1 * s_mb[1][b2];
        __hip_atomic_fetch_add(&pacc[((size_t)t * 2 + 0) * 512 + grp * 32 + b2], part,
                               __ATOMIC_RELAXED, __HIP_MEMORY_SCOPE_AGENT);
      }
    }
    grid_barrier(bc1, bc2, gfl, baridx++);

    // ---- S4: m1b (over m1a, in-block) + p1 partials ----
    {
      const float* m1a = m1aR + wo;
      float acc2[2] = {0.f, 0.f};
      float vm[4];
#pragma unroll
      for (int q = 0; q < 4; q++) vm[q] = m1a[(kb + q) * 32 + b];
      for (int kk = 0; kk < 32; kk += 4) {
        float nm[4];
        {
          int kn = kb + (kk < 28 ? kk + 4 : 4);
#pragma unroll
          for (int q = 0; q < 4; q++) nm[q] = m1a[(kn + q) * 32 + b];
        }
#pragma unroll
        for (int w = 0; w < 2; w++) {
          const float* wp = mW2 + (size_t)(512 + i0 + w) * 512;
          float4 w4 = *(const float4*)(wp + kb + kk);
          acc2[w] += dot4f(w4, vm);
        }
#pragma unroll
        for (int q = 0; q < 4; q++) vm[q] = nm[q];
      }
#pragma unroll
      for (int w = 0; w < 2; w++) red[u][w * 32 + b] = acc2[w];
      __syncthreads();
      if (tid < 64) {
        float s = 0.f;
#pragma unroll
        for (int uu = 0; uu < 16; uu++) s += red[uu][tid];
        int w = tid >> 5, b2 = tid & 31;
        s_mb[w][b2] = fmaxf(s + mb2[512 + i0 + w], 0.f);        // m1b cols
      }
      __syncthreads();
      if (tid >= 64 && tid < 96) {
        int b2 = tid - 64;
        float part = w3q0 * s_mb[0][b2] + w3q1 * s_mb[1][b2];
        __hip_atomic_fetch_add(&pacc[((size_t)t * 2 + 1) * 512 + grp * 32 + b2], part,
                               __ATOMIC_RELAXED, __HIP_MEMORY_SCOPE_AGENT);
      }
    }
    grid_barrier(bc1, bc2, gfl, baridx++);
  }

  // ---- final output column t = T-1 ----
  if (blockIdx.x == 0 && tid < 64) {
    int which = tid >> 5, b2 = tid & 31;
    const float* pp = pacc + ((size_t)(Tt - 1) * 2 + which) * 512;
    float s = mb3v;
#pragma unroll
    for (int g = 0; g < 16; g++) s += pp[g * 32 + b2];
    out[((size_t)b2 * Tt + (Tt - 1)) * 2 + which] = sigf(s);
  }
}

extern "C" void kernel_launch(void* const* d_in, const int* in_sizes, int n_in,
                              void* d_out, int out_size, void* d_ws, size_t ws_size,
                              hipStream_t stream)
{
  (void)in_sizes; (void)n_in; (void)out_size;
  const float* x    = (const float*)d_in[0];
  const float* Wih0 = (const float*)d_in[1];
  const float* Whh0 = (const float*)d_in[2];
  const float* bih0 = (const float*)d_in[3];
  const float* bhh0 = (const float*)d_in[4];
  const float* Wih  = (const float*)d_in[5];
  const float* Whh  = (const float*)d_in[6];
  const float* bih  = (const float*)d_in[7];
  const float* bhh  = (const float*)d_in[8];
  const float* mW1  = (const float*)d_in[9];
  const float* mb1  = (const float*)d_in[10];
  const float* mW2  = (const float*)d_in[11];
  const float* mb2  = (const float*)d_in[12];
  const float* mW3  = (const float*)d_in[13];
  const float* mb3  = (const float*)d_in[14];
  float* out = (float*)d_out;

  char* ws = (char*)d_ws;
  size_t off = 0;
  auto take = [&](size_t bytes) { size_t o = off; off = (off + bytes + 255) & ~(size_t)255; return o; };
  unsigned* bc1 = (unsigned*)(ws + take((size_t)NBAR * 16 * 16 * 4));
  unsigned* bc2 = (unsigned*)(ws + take((size_t)NBAR * 16 * 4));
  unsigned* gfl = (unsigned*)(ws + take((size_t)16 * 16 * 4));
  float* c0R  = (float*)(ws + take((size_t)PR * HB * 4));
  float* c1R  = (float*)(ws + take((size_t)PR * HB * 4));
  float* c2R  = (float*)(ws + take((size_t)PR * HB * 4));
  float* m0aR = (float*)(ws + take((size_t)PR * HB * 4));
  float* m1aR = (float*)(ws + take((size_t)PR * HB * 4));
  float* pacc = (float*)(ws + take((size_t)Tt * 2 * 512 * 4));
  size_t zero_bytes = off;
  float* GI0 = (float*)(ws + take((size_t)Tt * G3 * Bb * 4));
  if (ws_size < off) return;  // fail visibly rather than corrupt

  hipMemsetAsync(d_ws, 0, zero_bytes, stream);
  gi0_gemm<<<dim3(Tt, G3 / 128), 256, 0, stream>>>(x, Wih0, bih0, GI0);
  hrnn_persist<<<NBLK, NTHR, 0, stream>>>(Whh0, bhh0, Wih, Whh, bih, bhh,
      mW1, mb1, mW2, mb2, mW3, mb3, GI0,
      c0R, c1R, c2R, m0aR, m1aR, pacc, bc1, bc2, gfl, out);
}